// Round 5
// baseline (1744.303 us; speedup 1.0000x reference)
//
#include <hip/hip_runtime.h>
#include <hip/hip_bf16.h>

// Problem dims (fixed by reference): x[B*S=8192, E=2048], w1/w2[H=8192, E], w3[E, H]
#define M_ROWS 8192
#define E_DIM  2048
#define H_DIM  8192

typedef __attribute__((ext_vector_type(8))) short bf16x8;
typedef __attribute__((ext_vector_type(4))) float f32x4;
typedef __attribute__((ext_vector_type(4))) unsigned int uint4v;

__device__ __forceinline__ unsigned short f2bf_rne(float x) {
  unsigned u = __builtin_bit_cast(unsigned, x);
  u += 0x7FFFu + ((u >> 16) & 1u);
  return (unsigned short)(u >> 16);
}

__device__ __forceinline__ float bf2f(unsigned short b) {
  unsigned u = ((unsigned)b) << 16;
  return __builtin_bit_cast(float, u);
}

// ---------------- fp32 -> bf16 conversion (memory-bound, vectorized) ----------------
__global__ __launch_bounds__(256) void cvt_f32_bf16(const float* __restrict__ in,
                                                    unsigned short* __restrict__ out,
                                                    int n8) {
  int i = blockIdx.x * blockDim.x + threadIdx.x;
  if (i >= n8) return;
  const float4* p = (const float4*)(in + (size_t)i * 8);
  float4 a = p[0];
  float4 b = p[1];
  union { unsigned short us[8]; uint4v v; } r;
  r.us[0] = f2bf_rne(a.x); r.us[1] = f2bf_rne(a.y);
  r.us[2] = f2bf_rne(a.z); r.us[3] = f2bf_rne(a.w);
  r.us[4] = f2bf_rne(b.x); r.us[5] = f2bf_rne(b.y);
  r.us[6] = f2bf_rne(b.z); r.us[7] = f2bf_rne(b.w);
  *(uint4v*)(out + (size_t)i * 8) = r.v;
}

// ---------------- async global -> LDS, 16B per lane ----------------
__device__ __forceinline__ void gld_lds16(const unsigned short* g, unsigned short* l) {
  __builtin_amdgcn_global_load_lds(
      (const __attribute__((address_space(1))) unsigned int*)g,
      (__attribute__((address_space(3))) unsigned int*)l, 16, 0, 0);
}

#define VMCNT(n)   asm volatile("s_waitcnt vmcnt(" #n ")" ::: "memory")
#define LGKMCNT(n) asm volatile("s_waitcnt lgkmcnt(" #n ")" ::: "memory")

// =============== 256x256 fine-interleaved 4-phase GEMM: C = A[M,K] * B[N,K]^T ===============
// 512 threads (8 waves, 2Mx4N), BK=64, 128KiB double-buffered LDS.
// Per phase: balanced {<=12 ds_read_b128, 1 stage unit (2 glds), counted lgkmcnt, 16 MFMA}.
// Stage units aligned to quadrant read row-sets (8-row-chunk unions; legal because each
// wave's global_load_lds writes one contiguous 1KiB):
//   A_U0 = rows {0-63,128-191} (af[0-3]) ; A_U1 = rows {64-127,192-255} (af[4-7])
//   B_U0 = rows {0-31,64-95,128-159,192-223} (bf[0-1]) ; B_U2 = +32 (bf[2-3])
// Schedule (tile t, cur=t&1):
//   ph0: rd af[4-7](8) | stage B_U0(t+1)->buf[!cur] | bar | lgkm(8)  | Q0 | bar
//   ph1: rd bf[2-3](4) | stage A_U0(t+2)->buf[cur]  | bar | lgkm(4)  | Q1 | bar
//   ph2:               | stage A_U1(t+2)->buf[cur]  | bar | lgkm(0)  | Q2 | bar
//   ph3: vmcnt(4) | bar | rd next af[0-3]+bf[0-1](12) | stage B_U2(t+2) | Q3 | bar
// vmcnt(4) at ph3: outstanding = {t-1:p1,p2,p3; t:p0,p1,p2} = 12 loads; drains oldest 8
// = ALL of tile t+1's units (incl. t-ph0's B_U0) before any wave reads buf[!cur];
// leaves 4 (t+2's A units) in flight. Never drains to 0 in steady state.
// WAR safety: each staged region's reads are register-drained >=1 barrier before the
// stage issues (Q0 reads drained ph0, af[4-7] ph1, bf[2-3] ph2). Tail: staged tile
// indices clamp to NT-1 (redundant loads, regions proven read-complete, data unused).
// EPI=0: fp32 store; EPI=1: bf16 store; EPI=2: bf16 silu(Gate[idx]) * acc store.
template <int EPI>
__global__ __launch_bounds__(512, 2)
void gemm256(const unsigned short* __restrict__ A,
             const unsigned short* __restrict__ B,
             const unsigned short* __restrict__ Gate,
             void* __restrict__ Cout,
             int M, int N, int K) {
  __shared__ unsigned short lA[2][16384];
  __shared__ unsigned short lB[2][16384];

  const int tid = threadIdx.x;
  const int lane = tid & 63;
  const int wave = tid >> 6;
  const int wr = wave >> 2;   // 0..1  (128 output rows each)
  const int wc = wave & 3;    // 0..3  (64 output cols each)
  const int lr = lane & 15, lk = lane >> 4;

  // bijective XCD swizzle (nwg % 8 == 0 for all launches here)
  const int gx = gridDim.x;
  const int nwg = gx * gridDim.y;
  const int wg = blockIdx.y * gx + blockIdx.x;
  const int swz = (wg & 7) * (nwg >> 3) + (wg >> 3);
  const int bcol = swz % gx, brow = swz / gx;

  const unsigned short* Ag = A + (size_t)brow * 256 * K;
  const unsigned short* Bg = B + (size_t)bcol * 256 * K;

  f32x4 acc[8][4] = {};
  const int NT = K >> 6;

  // stage one 128-row unit (8192 elems). kind: 0=A_U0 1=A_U1 2=B_U0 3=B_U2.
  // LDS dest linear per wave (1KiB chunks); global src pre-swizzled (slot ^ row&7).
  auto stage_unit = [&](const unsigned short* gbase, unsigned short* lds, int kind) {
#pragma unroll
    for (int i = 0; i < 2; ++i) {
      int p = i * 4096 + tid * 8;          // elem index within unit, 0..8191
      int ru = p >> 6;                     // row-in-unit 0..127
      int row;
      if (kind < 2) row = ((ru & 63) | ((ru >> 6) << 7)) + ((kind & 1) << 6);
      else          row = ((ru & 31) | ((ru >> 5) << 6)) + ((kind & 1) << 5);
      int slot = (p >> 3) & 7;             // physical 8-elem slot within row
      gld_lds16(gbase + (size_t)row * K + (size_t)(slot ^ (row & 7)) * 8,
                lds + row * 64 + slot * 8);
    }
  };

  bf16x8 af[8][2], bf[4][2];
  const int xsw = (lr & 7) << 3;  // read-side swizzle XOR (element units)

  // ---------------- prologue ----------------
  stage_unit(Ag, &lA[0][0], 0);
  stage_unit(Ag, &lA[0][0], 1);
  stage_unit(Bg, &lB[0][0], 2);
  stage_unit(Bg, &lB[0][0], 3);
  stage_unit(Ag + 64, &lA[1][0], 0);   // tile1 A_U0
  stage_unit(Ag + 64, &lA[1][0], 1);   // tile1 A_U1
  stage_unit(Bg + 64, &lB[1][0], 3);   // tile1 B_U2 (B_U0(1) staged at t=0 ph0)
  VMCNT(6);                            // tile0's 8 loads landed (per wave) ...
  __builtin_amdgcn_s_barrier();        // ... and across all waves
  // pre-read tile0 Q0 operands ("prev ph3" for t=0)
#pragma unroll
  for (int m = 0; m < 4; ++m) {
    int r = wr * 128 + m * 16 + lr;
    af[m][0] = *(const bf16x8*)&lA[0][(r * 64 + lk * 8) ^ xsw];
    af[m][1] = *(const bf16x8*)&lA[0][(r * 64 + 32 + lk * 8) ^ xsw];
  }
#pragma unroll
  for (int n = 0; n < 2; ++n) {
    int r = wc * 64 + n * 16 + lr;
    bf[n][0] = *(const bf16x8*)&lB[0][(r * 64 + lk * 8) ^ xsw];
    bf[n][1] = *(const bf16x8*)&lB[0][(r * 64 + 32 + lk * 8) ^ xsw];
  }

  for (int t = 0; t < NT; ++t) {
    const int cur = t & 1;
    const unsigned short* lAc = &lA[cur][0];
    const unsigned short* lBc = &lB[cur][0];
    const unsigned short* lAx = &lA[cur ^ 1][0];   // tile t+1 data
    const unsigned short* lBx = &lB[cur ^ 1][0];
    unsigned short* lAw  = &lA[cur][0];            // t+2 lands in cur parity
    unsigned short* lBw  = &lB[cur][0];
    unsigned short* lBw1 = &lB[cur ^ 1][0];        // t+1 parity
    const int s1 = (t + 1 < NT) ? t + 1 : NT - 1;
    const int s2 = (t + 2 < NT) ? t + 2 : NT - 1;
    const unsigned short* Ag2 = Ag + (size_t)s2 * 64;
    const unsigned short* Bg1 = Bg + (size_t)s1 * 64;
    const unsigned short* Bg2 = Bg + (size_t)s2 * 64;

    // ---- ph0: rd af[4-7] | stage B_U0(t+1) | bar | lgkm(8) | Q0 | bar
#pragma unroll
    for (int m = 4; m < 8; ++m) {
      int r = wr * 128 + m * 16 + lr;
      af[m][0] = *(const bf16x8*)&lAc[(r * 64 + lk * 8) ^ xsw];
      af[m][1] = *(const bf16x8*)&lAc[(r * 64 + 32 + lk * 8) ^ xsw];
    }
    stage_unit(Bg1, lBw1, 2);
    __builtin_amdgcn_s_barrier();
    LGKMCNT(8);
    __builtin_amdgcn_s_setprio(1);
#pragma unroll
    for (int m = 0; m < 4; ++m)
#pragma unroll
      for (int n = 0; n < 2; ++n)
#pragma unroll
        for (int ks = 0; ks < 2; ++ks)
          acc[m][n] = __builtin_amdgcn_mfma_f32_16x16x32_bf16(af[m][ks], bf[n][ks], acc[m][n], 0, 0, 0);
    __builtin_amdgcn_s_setprio(0);
    __builtin_amdgcn_s_barrier();

    // ---- ph1: rd bf[2-3] | stage A_U0(t+2) | bar | lgkm(4) | Q1 | bar
#pragma unroll
    for (int n = 2; n < 4; ++n) {
      int r = wc * 64 + n * 16 + lr;
      bf[n][0] = *(const bf16x8*)&lBc[(r * 64 + lk * 8) ^ xsw];
      bf[n][1] = *(const bf16x8*)&lBc[(r * 64 + 32 + lk * 8) ^ xsw];
    }
    stage_unit(Ag2, lAw, 0);
    __builtin_amdgcn_s_barrier();
    LGKMCNT(4);
    __builtin_amdgcn_s_setprio(1);
#pragma unroll
    for (int m = 4; m < 8; ++m)
#pragma unroll
      for (int n = 0; n < 2; ++n)
#pragma unroll
        for (int ks = 0; ks < 2; ++ks)
          acc[m][n] = __builtin_amdgcn_mfma_f32_16x16x32_bf16(af[m][ks], bf[n][ks], acc[m][n], 0, 0, 0);
    __builtin_amdgcn_s_setprio(0);
    __builtin_amdgcn_s_barrier();

    // ---- ph2: stage A_U1(t+2) | bar | lgkm(0) | Q2 | bar
    stage_unit(Ag2, lAw, 1);
    __builtin_amdgcn_s_barrier();
    LGKMCNT(0);
    __builtin_amdgcn_s_setprio(1);
#pragma unroll
    for (int m = 0; m < 4; ++m)
#pragma unroll
      for (int n = 2; n < 4; ++n)
#pragma unroll
        for (int ks = 0; ks < 2; ++ks)
          acc[m][n] = __builtin_amdgcn_mfma_f32_16x16x32_bf16(af[m][ks], bf[n][ks], acc[m][n], 0, 0, 0);
    __builtin_amdgcn_s_setprio(0);
    __builtin_amdgcn_s_barrier();

    // ---- ph3: vmcnt(4) | bar | rd next Q0 (12) | stage B_U2(t+2) | Q3 | bar
    VMCNT(4);
    __builtin_amdgcn_s_barrier();   // after this, ALL waves' t+1 loads have landed
#pragma unroll
    for (int m = 0; m < 4; ++m) {
      int r = wr * 128 + m * 16 + lr;
      af[m][0] = *(const bf16x8*)&lAx[(r * 64 + lk * 8) ^ xsw];
      af[m][1] = *(const bf16x8*)&lAx[(r * 64 + 32 + lk * 8) ^ xsw];
    }
#pragma unroll
    for (int n = 0; n < 2; ++n) {
      int r = wc * 64 + n * 16 + lr;
      bf[n][0] = *(const bf16x8*)&lBx[(r * 64 + lk * 8) ^ xsw];
      bf[n][1] = *(const bf16x8*)&lBx[(r * 64 + 32 + lk * 8) ^ xsw];
    }
    stage_unit(Bg2, lBw, 3);
    __builtin_amdgcn_s_setprio(1);
#pragma unroll
    for (int m = 4; m < 8; ++m)
#pragma unroll
      for (int n = 2; n < 4; ++n)
#pragma unroll
        for (int ks = 0; ks < 2; ++ks)
          acc[m][n] = __builtin_amdgcn_mfma_f32_16x16x32_bf16(af[m][ks], bf[n][ks], acc[m][n], 0, 0, 0);
    __builtin_amdgcn_s_setprio(0);
    __builtin_amdgcn_s_barrier();
  }

  // Epilogue. C/D frag layout (measured, m89/m91): col = lane&15, row = (lane>>4)*4 + j
  const int row0 = brow * 256 + wr * 128 + lk * 4;
  const int col0 = bcol * 256 + wc * 64 + lr;
#pragma unroll
  for (int m = 0; m < 8; ++m) {
#pragma unroll
    for (int n = 0; n < 4; ++n) {
#pragma unroll
      for (int j = 0; j < 4; ++j) {
        size_t idx = (size_t)(row0 + m * 16 + j) * N + (col0 + n * 16);
        float v = acc[m][n][j];
        if constexpr (EPI == 0) {
          ((float*)Cout)[idx] = v;
        } else if constexpr (EPI == 1) {
          ((unsigned short*)Cout)[idx] = f2bf_rne(v);
        } else {
          float g = bf2f(Gate[idx]);
          float s = g / (1.0f + __expf(-g));  // silu
          ((unsigned short*)Cout)[idx] = f2bf_rne(s * v);
        }
      }
    }
  }
}

extern "C" void kernel_launch(void* const* d_in, const int* in_sizes, int n_in,
                              void* d_out, int out_size, void* d_ws, size_t ws_size,
                              hipStream_t stream) {
  const float* x  = (const float*)d_in[0];
  const float* w1 = (const float*)d_in[1];
  const float* w2 = (const float*)d_in[2];
  const float* w3 = (const float*)d_in[3];
  float* out = (float*)d_out;

  const int M = M_ROWS, E = E_DIM, H = H_DIM;

  // ws layout (bf16 elements):
  //   [0, 32MB)   xb   (reused for w3b after up-GEMM)
  //   [32, 64MB)  w1b  (reused for w2b after gate-GEMM)
  //   [64, 192MB) gate -> h (silu-mul written in-place)
  unsigned short* xb  = (unsigned short*)d_ws;
  unsigned short* w1b = xb + (size_t)M * E;
  unsigned short* gb  = w1b + (size_t)H * E;
  unsigned short* w2b = w1b;  // safe: cvt(w2) is stream-ordered after gate-GEMM reads w1b
  unsigned short* w3b = xb;   // safe: cvt(w3) is stream-ordered after up-GEMM reads xb

  const int n8 = (M * E) / 8;  // == (H*E)/8 == (E*H)/8 == 2097152
  cvt_f32_bf16<<<dim3(n8 / 256), 256, 0, stream>>>(x, xb, n8);
  cvt_f32_bf16<<<dim3(n8 / 256), 256, 0, stream>>>(w1, w1b, n8);

  // gate = x w1^T  -> bf16 [M, H]
  gemm256<1><<<dim3(H / 256, M / 256), 512, 0, stream>>>(xb, w1b, nullptr, gb, M, H, E);

  cvt_f32_bf16<<<dim3(n8 / 256), 256, 0, stream>>>(w2, w2b, n8);

  // h = silu(gate) * (x w2^T) -> bf16 [M, H], in-place over gate
  gemm256<2><<<dim3(H / 256, M / 256), 512, 0, stream>>>(xb, w2b, gb, gb, M, H, E);

  cvt_f32_bf16<<<dim3(n8 / 256), 256, 0, stream>>>(w3, w3b, n8);

  // out = h w3^T -> fp32 [M, E]
  gemm256<0><<<dim3(E / 256, M / 256), 512, 0, stream>>>(gb, w3b, nullptr, out, M, E, H);
}

// Round 6
// 1397.040 us; speedup vs baseline: 1.2486x; 1.2486x over previous
//
#include <hip/hip_runtime.h>
#include <hip/hip_bf16.h>

// Problem dims (fixed by reference): x[B*S=8192, E=2048], w1/w2[H=8192, E], w3[E, H]
#define M_ROWS 8192
#define E_DIM  2048
#define H_DIM  8192

typedef __attribute__((ext_vector_type(8))) short bf16x8;
typedef __attribute__((ext_vector_type(4))) float f32x4;
typedef __attribute__((ext_vector_type(4))) unsigned int uint4v;

__device__ __forceinline__ unsigned short f2bf_rne(float x) {
  unsigned u = __builtin_bit_cast(unsigned, x);
  u += 0x7FFFu + ((u >> 16) & 1u);
  return (unsigned short)(u >> 16);
}

__device__ __forceinline__ float bf2f(unsigned short b) {
  unsigned u = ((unsigned)b) << 16;
  return __builtin_bit_cast(float, u);
}

// ---------------- fp32 -> bf16 conversion (memory-bound, vectorized) ----------------
__global__ __launch_bounds__(256) void cvt_f32_bf16(const float* __restrict__ in,
                                                    unsigned short* __restrict__ out,
                                                    int n8) {
  int i = blockIdx.x * blockDim.x + threadIdx.x;
  if (i >= n8) return;
  const float4* p = (const float4*)(in + (size_t)i * 8);
  float4 a = p[0];
  float4 b = p[1];
  union { unsigned short us[8]; uint4v v; } r;
  r.us[0] = f2bf_rne(a.x); r.us[1] = f2bf_rne(a.y);
  r.us[2] = f2bf_rne(a.z); r.us[3] = f2bf_rne(a.w);
  r.us[4] = f2bf_rne(b.x); r.us[5] = f2bf_rne(b.y);
  r.us[6] = f2bf_rne(b.z); r.us[7] = f2bf_rne(b.w);
  *(uint4v*)(out + (size_t)i * 8) = r.v;
}

// ---------------- async global -> LDS, 16B per lane ----------------
__device__ __forceinline__ void gld_lds16(const unsigned short* g, unsigned short* l) {
  __builtin_amdgcn_global_load_lds(
      (const __attribute__((address_space(1))) unsigned int*)g,
      (__attribute__((address_space(3))) unsigned int*)l, 16, 0, 0);
}

#define VMCNT(n) asm volatile("s_waitcnt vmcnt(" #n ")" ::: "memory")

// =============== 256x256 GEMM, reads ONE PHASE AHEAD of consuming MFMA ===============
// C[M,N] = A[M,K]*B[N,K]^T. 512 threads (8 waves 2Mx4N), BK=64, 128KiB dbuf LDS,
// XOR-swizzled reads (elem ^= (lr&7)<<3) via pre-swizzled global src (linear LDS dest),
// bijective XCD swizzle, setprio on MFMA.
// Phase skeleton: [stage; (vmcnt); barrier; ds_reads-for-NEXT-phase; MFMA-on-prev-reads;
// barrier]. The compiler's auto-lgkmcnt before each MFMA is satisfied-on-arrival
// (operand reads were issued one phase earlier and drained during the prior MFMA
// segment), so LDS serving overlaps MFMA instead of alternating with it.
// Per-tile schedule (tile t in buf[t&1]; kn1=(t+1)*64, kn2=(t+2)*64):
//  ph1: stage B0(t+1)->buf[!cur] | bar | rd af[4-7](t)  | Q0(af[0-3],bf[0-1]) | bar
//  ph2: stage B1(t+1)->buf[!cur] | bar | rd bf[2-3](t)  | Q1(af[4-7],bf[0-1]) | bar
//  ph3: stage A0(t+2)->buf[cur]  | bar |                | Q2(af[0-3],bf[2-3]) | bar
//  ph4: stage A1(t+2)->buf[cur]  | vmcnt(4) | bar | rd af[0-3]+bf[0-1](t+1, 12 rds)
//                                                  | Q3(af[4-7],bf[2-3]) | bar
// vmcnt(4) per-wave induction: after t-1's wait, in flight = A0,A1(t+1) (4 instr);
// t issues B0,B1(t+1),A0,A1(t+2) (+8 = 12); drain to 4 = all of tile t+1 landed,
// t+2's A stays in flight. Tail: vmcnt(0) when t+2>=NT (t's ph3/4 stages skipped,
// must still drain B(t+1) for the ph4 reads); ph4 reads skipped when t+1>=NT.
// WAR safety (stage target region vs last reads of old data, all >=1 barrier apart):
//  B0/B1(t+1) over B(t-1): bf reads of t-1 retired by t-1's Q-waitcnts. A0(t+2) over
//  A0(t): af[0-3](t) retired by Q0 (ph1), af[4-7](t) by Q1 (ph2) < ph3. A1 likewise.
// EPI=0: fp32 store; EPI=1: bf16 store; EPI=2: bf16 silu(Gate[idx]) * acc store.
template <int EPI>
__global__ __launch_bounds__(512, 2)
void gemm256(const unsigned short* __restrict__ A,
             const unsigned short* __restrict__ B,
             const unsigned short* __restrict__ Gate,
             void* __restrict__ Cout,
             int M, int N, int K) {
  __shared__ unsigned short lA[2][16384];  // 2 x (256x64) bf16, as 2 halves of 128x64
  __shared__ unsigned short lB[2][16384];

  const int tid = threadIdx.x;
  const int lane = tid & 63;
  const int wave = tid >> 6;
  const int wr = wave >> 2;   // 0..1  (128 output rows each)
  const int wc = wave & 3;    // 0..3  (64 output cols each)
  const int lr = lane & 15, lk = lane >> 4;

  // bijective XCD swizzle (nwg % 8 == 0 for all launches here)
  const int gx = gridDim.x;
  const int nwg = gx * gridDim.y;
  const int wg = blockIdx.y * gx + blockIdx.x;
  const int swz = (wg & 7) * (nwg >> 3) + (wg >> 3);
  const int bcol = swz % gx, brow = swz / gx;

  const unsigned short* Ag = A + (size_t)brow * 256 * K;
  const unsigned short* Bg = B + (size_t)bcol * 256 * K;

  f32x4 acc[8][4] = {};
  const int NT = K >> 6;

  // stage one 128x64 half-tile: linear LDS dest (lane*16B), inverse-swizzled global src
  auto stage = [&](const unsigned short* gbase, unsigned short* ldsh) {
#pragma unroll
    for (int i = 0; i < 2; ++i) {
      int p = i * 4096 + tid * 8;               // physical element offset in half
      int row = p >> 6;                          // 0..127
      int lslot = ((p >> 3) & 7) ^ (row & 7);    // logical 8-elem slot
      gld_lds16(gbase + (size_t)row * K + lslot * 8, ldsh + p);
    }
  };

  const int xsw = (lr & 7) << 3;  // read-side swizzle XOR (element units)
  bf16x8 af[8][2], bf[4][2];      // loop-carried: read one phase before use

  // ---------------- prologue: tile0 full + tile1 A halves; preread tile0 Q0 ops ----------------
  stage(Ag, &lA[0][0]);
  stage(Ag + (size_t)128 * K, &lA[0][8192]);
  stage(Bg, &lB[0][0]);
  stage(Bg + (size_t)128 * K, &lB[0][8192]);
  if (NT > 1) {
    stage(Ag + 64, &lA[1][0]);
    stage(Ag + (size_t)128 * K + 64, &lA[1][8192]);
    VMCNT(4);   // tile0's 8 loads landed; tile1's A (4) in flight
  } else {
    VMCNT(0);
  }
  __builtin_amdgcn_s_barrier();
#pragma unroll
  for (int m = 0; m < 4; ++m) {
    int r = wr * 128 + m * 16 + lr;
    af[m][0] = *(const bf16x8*)&lA[0][(r * 64 + lk * 8) ^ xsw];
    af[m][1] = *(const bf16x8*)&lA[0][(r * 64 + 32 + lk * 8) ^ xsw];
  }
#pragma unroll
  for (int n = 0; n < 2; ++n) {
    int r = wc * 64 + n * 16 + lr;
    bf[n][0] = *(const bf16x8*)&lB[0][(r * 64 + lk * 8) ^ xsw];
    bf[n][1] = *(const bf16x8*)&lB[0][(r * 64 + 32 + lk * 8) ^ xsw];
  }

  for (int t = 0; t < NT; ++t) {
    const int cur = t & 1;
    const unsigned short* lAc = &lA[cur][0];       // tile t
    const unsigned short* lBc = &lB[cur][0];
    const unsigned short* lAx = &lA[cur ^ 1][0];   // tile t+1
    const unsigned short* lBx = &lB[cur ^ 1][0];
    unsigned short* lAn = &lA[cur][0];             // A(t+2) dest (parity of t)
    unsigned short* lBn = &lB[cur ^ 1][0];         // B(t+1) dest
    const size_t kn1 = (size_t)(t + 1) * 64;
    const size_t kn2 = (size_t)(t + 2) * 64;
    const bool pf1 = (t + 1 < NT);
    const bool pf2 = (t + 2 < NT);

    // ---- ph1: stage B0(t+1) | bar | rd af[4-7] | Q0 | bar
    if (pf1) stage(Bg + kn1, lBn);
    __builtin_amdgcn_s_barrier();
#pragma unroll
    for (int m = 4; m < 8; ++m) {
      int r = wr * 128 + m * 16 + lr;
      af[m][0] = *(const bf16x8*)&lAc[(r * 64 + lk * 8) ^ xsw];
      af[m][1] = *(const bf16x8*)&lAc[(r * 64 + 32 + lk * 8) ^ xsw];
    }
    __builtin_amdgcn_s_setprio(1);
#pragma unroll
    for (int m = 0; m < 4; ++m)
#pragma unroll
      for (int n = 0; n < 2; ++n)
#pragma unroll
        for (int ks = 0; ks < 2; ++ks)
          acc[m][n] = __builtin_amdgcn_mfma_f32_16x16x32_bf16(af[m][ks], bf[n][ks], acc[m][n], 0, 0, 0);
    __builtin_amdgcn_s_setprio(0);
    __builtin_amdgcn_s_barrier();

    // ---- ph2: stage B1(t+1) | bar | rd bf[2-3] | Q1 | bar
    if (pf1) stage(Bg + (size_t)128 * K + kn1, lBn + 8192);
    __builtin_amdgcn_s_barrier();
#pragma unroll
    for (int n = 2; n < 4; ++n) {
      int r = wc * 64 + n * 16 + lr;
      bf[n][0] = *(const bf16x8*)&lBc[(r * 64 + lk * 8) ^ xsw];
      bf[n][1] = *(const bf16x8*)&lBc[(r * 64 + 32 + lk * 8) ^ xsw];
    }
    __builtin_amdgcn_s_setprio(1);
#pragma unroll
    for (int m = 4; m < 8; ++m)
#pragma unroll
      for (int n = 0; n < 2; ++n)
#pragma unroll
        for (int ks = 0; ks < 2; ++ks)
          acc[m][n] = __builtin_amdgcn_mfma_f32_16x16x32_bf16(af[m][ks], bf[n][ks], acc[m][n], 0, 0, 0);
    __builtin_amdgcn_s_setprio(0);
    __builtin_amdgcn_s_barrier();

    // ---- ph3: stage A0(t+2) | bar | (no reads) | Q2 | bar
    if (pf2) stage(Ag + kn2, lAn);
    __builtin_amdgcn_s_barrier();
    __builtin_amdgcn_s_setprio(1);
#pragma unroll
    for (int m = 0; m < 4; ++m)
#pragma unroll
      for (int n = 2; n < 4; ++n)
#pragma unroll
        for (int ks = 0; ks < 2; ++ks)
          acc[m][n] = __builtin_amdgcn_mfma_f32_16x16x32_bf16(af[m][ks], bf[n][ks], acc[m][n], 0, 0, 0);
    __builtin_amdgcn_s_setprio(0);
    __builtin_amdgcn_s_barrier();

    // ---- ph4: stage A1(t+2) | vmcnt | bar | rd next af[0-3]+bf[0-1] | Q3 | bar
    if (pf2) stage(Ag + (size_t)128 * K + kn2, lAn + 8192);
    if (pf2) { VMCNT(4); } else { VMCNT(0); }   // all of tile t+1 landed
    __builtin_amdgcn_s_barrier();
    if (pf1) {
#pragma unroll
      for (int m = 0; m < 4; ++m) {
        int r = wr * 128 + m * 16 + lr;
        af[m][0] = *(const bf16x8*)&lAx[(r * 64 + lk * 8) ^ xsw];
        af[m][1] = *(const bf16x8*)&lAx[(r * 64 + 32 + lk * 8) ^ xsw];
      }
#pragma unroll
      for (int n = 0; n < 2; ++n) {
        int r = wc * 64 + n * 16 + lr;
        bf[n][0] = *(const bf16x8*)&lBx[(r * 64 + lk * 8) ^ xsw];
        bf[n][1] = *(const bf16x8*)&lBx[(r * 64 + 32 + lk * 8) ^ xsw];
      }
    }
    __builtin_amdgcn_s_setprio(1);
#pragma unroll
    for (int m = 4; m < 8; ++m)
#pragma unroll
      for (int n = 2; n < 4; ++n)
#pragma unroll
        for (int ks = 0; ks < 2; ++ks)
          acc[m][n] = __builtin_amdgcn_mfma_f32_16x16x32_bf16(af[m][ks], bf[n][ks], acc[m][n], 0, 0, 0);
    __builtin_amdgcn_s_setprio(0);
    __builtin_amdgcn_s_barrier();
  }

  // Epilogue. C/D frag layout (measured, m89/m91): col = lane&15, row = (lane>>4)*4 + j
  const int row0 = brow * 256 + wr * 128 + lk * 4;
  const int col0 = bcol * 256 + wc * 64 + lr;
#pragma unroll
  for (int m = 0; m < 8; ++m) {
#pragma unroll
    for (int n = 0; n < 4; ++n) {
#pragma unroll
      for (int j = 0; j < 4; ++j) {
        size_t idx = (size_t)(row0 + m * 16 + j) * N + (col0 + n * 16);
        float v = acc[m][n][j];
        if constexpr (EPI == 0) {
          ((float*)Cout)[idx] = v;
        } else if constexpr (EPI == 1) {
          ((unsigned short*)Cout)[idx] = f2bf_rne(v);
        } else {
          float g = bf2f(Gate[idx]);
          float s = g / (1.0f + __expf(-g));  // silu
          ((unsigned short*)Cout)[idx] = f2bf_rne(s * v);
        }
      }
    }
  }
}

extern "C" void kernel_launch(void* const* d_in, const int* in_sizes, int n_in,
                              void* d_out, int out_size, void* d_ws, size_t ws_size,
                              hipStream_t stream) {
  const float* x  = (const float*)d_in[0];
  const float* w1 = (const float*)d_in[1];
  const float* w2 = (const float*)d_in[2];
  const float* w3 = (const float*)d_in[3];
  float* out = (float*)d_out;

  const int M = M_ROWS, E = E_DIM, H = H_DIM;

  // ws layout (bf16 elements):
  //   [0, 32MB)   xb   (reused for w3b after up-GEMM)
  //   [32, 64MB)  w1b  (reused for w2b after gate-GEMM)
  //   [64, 192MB) gate -> h (silu-mul written in-place)
  unsigned short* xb  = (unsigned short*)d_ws;
  unsigned short* w1b = xb + (size_t)M * E;
  unsigned short* gb  = w1b + (size_t)H * E;
  unsigned short* w2b = w1b;  // safe: cvt(w2) is stream-ordered after gate-GEMM reads w1b
  unsigned short* w3b = xb;   // safe: cvt(w3) is stream-ordered after up-GEMM reads xb

  const int n8 = (M * E) / 8;  // == (H*E)/8 == (E*H)/8 == 2097152
  cvt_f32_bf16<<<dim3(n8 / 256), 256, 0, stream>>>(x, xb, n8);
  cvt_f32_bf16<<<dim3(n8 / 256), 256, 0, stream>>>(w1, w1b, n8);

  // gate = x w1^T  -> bf16 [M, H]
  gemm256<1><<<dim3(H / 256, M / 256), 512, 0, stream>>>(xb, w1b, nullptr, gb, M, H, E);

  cvt_f32_bf16<<<dim3(n8 / 256), 256, 0, stream>>>(w2, w2b, n8);

  // h = silu(gate) * (x w2^T) -> bf16 [M, H], in-place over gate
  gemm256<2><<<dim3(H / 256, M / 256), 512, 0, stream>>>(xb, w2b, gb, gb, M, H, E);

  cvt_f32_bf16<<<dim3(n8 / 256), 256, 0, stream>>>(w3, w3b, n8);

  // out = h w3^T -> fp32 [M, E]
  gemm256<0><<<dim3(E / 256, M / 256), 512, 0, stream>>>(gb, w3b, nullptr, out, M, E, H);
}

// Round 7
// 871.664 us; speedup vs baseline: 2.0011x; 1.6027x over previous
//
#include <hip/hip_runtime.h>
#include <hip/hip_bf16.h>

// Problem dims (fixed by reference): x[B*S=8192, E=2048], w1/w2[H=8192, E], w3[E, H]
#define M_ROWS 8192
#define E_DIM  2048
#define H_DIM  8192

typedef __attribute__((ext_vector_type(8))) short bf16x8;
typedef __attribute__((ext_vector_type(4))) float f32x4;
typedef __attribute__((ext_vector_type(4))) unsigned int uint4v;

__device__ __forceinline__ unsigned short f2bf_rne(float x) {
  unsigned u = __builtin_bit_cast(unsigned, x);
  u += 0x7FFFu + ((u >> 16) & 1u);
  return (unsigned short)(u >> 16);
}

__device__ __forceinline__ float bf2f(unsigned short b) {
  unsigned u = ((unsigned)b) << 16;
  return __builtin_bit_cast(float, u);
}

// ---------------- fp32 -> bf16 conversion (memory-bound, vectorized) ----------------
__global__ __launch_bounds__(256) void cvt_f32_bf16(const float* __restrict__ in,
                                                    unsigned short* __restrict__ out,
                                                    int n8) {
  int i = blockIdx.x * blockDim.x + threadIdx.x;
  if (i >= n8) return;
  const float4* p = (const float4*)(in + (size_t)i * 8);
  float4 a = p[0];
  float4 b = p[1];
  union { unsigned short us[8]; uint4v v; } r;
  r.us[0] = f2bf_rne(a.x); r.us[1] = f2bf_rne(a.y);
  r.us[2] = f2bf_rne(a.z); r.us[3] = f2bf_rne(a.w);
  r.us[4] = f2bf_rne(b.x); r.us[5] = f2bf_rne(b.y);
  r.us[6] = f2bf_rne(b.z); r.us[7] = f2bf_rne(b.w);
  *(uint4v*)(out + (size_t)i * 8) = r.v;
}

// ---------------- async global -> LDS, 16B per lane ----------------
__device__ __forceinline__ void gld_lds16(const unsigned short* g, unsigned short* l) {
  __builtin_amdgcn_global_load_lds(
      (const __attribute__((address_space(1))) unsigned int*)g,
      (__attribute__((address_space(3))) unsigned int*)l, 16, 0, 0);
}

#define VMCNT(n)   asm volatile("s_waitcnt vmcnt(" #n ")" ::: "memory")

// =============== 256x256 8-phase/2-K-tile GEMM (m201 cadence): C = A[M,K]*B[N,K]^T ==========
// 512 threads (8 waves 2Mx4N), BK=64, buf0=even K-tiles buf1=odd (128KiB LDS).
// Per phase (template-verbatim): { ds_reads-for-THIS-phase's-MFMA; stage; [lgkm(8) if 12 rds];
//   barrier; lgkmcnt(0); sched_barrier; setprio(1); 16 MFMA (one C-quadrant); setprio(0);
//   [vmcnt(6) at ph4/ph8 only]; barrier }.
// Read distribution per K-tile: ph1: af[0-3]+bf[0-1] (12); ph2: bf[2-3] (4); ph3: af[4-7] (8);
// ph4: none. Quadrants: Q(0,0), Q(0,2), Q(4,0), Q(4,2).
// Stage cadence (1-2 halves/phase, deadline order; t even):
//   ph1: A.H1(t+1)          ph3: B.H0(t+2)   ph4: B.H1(t+2), A.H0(t+2)
//   ph5: A.H1(t+2)          ph7: B.H0(t+3)   ph8: B.H1(t+3), A.H0(t+3)
// WAR ledger (stage >= 1 barrier after last read retires; reads retire at consuming
// phase's lgkmcnt(0)):  B(t) last read ph2 -> B(t+2) stages ph3/ph4 OK.  A(t) last read
// ph3 -> A(t+2) stages ph4/ph5 OK.  B(t+1) last read ph6 -> B(t+3) ph7/ph8 OK.  A(t+1)
// last read ph7 -> A(t+3) ph8 + next-ph1 OK.  Tail: source k clamped to NT-1, dest
// regions unchanged (read-complete, data unread).
// vmcnt(6) induction (loads; 2/half): at ph4, outstanding = {B.H0,B.H1,A.H0(t+1)@prev
// ph7/ph8, A.H1(t+1)@ph1, B.H0,B.H1,A.H0(t+2)@ph3/ph4} = 14 -> drain 8 = tile t+1
// complete (ages 3-5 phases), 6 in flight.  ph8 symmetric: tile t+2 complete.
// EPI=0: fp32 store; EPI=1: bf16 store; EPI=2: bf16 silu(Gate[idx]) * acc store.
template <int EPI>
__global__ __launch_bounds__(512, 2)
void gemm256(const unsigned short* __restrict__ A,
             const unsigned short* __restrict__ B,
             const unsigned short* __restrict__ Gate,
             void* __restrict__ Cout,
             int M, int N, int K) {
  __shared__ unsigned short lA[2][16384];  // [parity][half*8192 + row*64 + col]
  __shared__ unsigned short lB[2][16384];

  const int tid = threadIdx.x;
  const int lane = tid & 63;
  const int wave = tid >> 6;
  const int wr = wave >> 2;   // 0..1  (128 output rows each)
  const int wc = wave & 3;    // 0..3  (64 output cols each)
  const int lr = lane & 15, lk = lane >> 4;

  // bijective XCD swizzle (nwg % 8 == 0 for all launches here)
  const int gx = gridDim.x;
  const int nwg = gx * gridDim.y;
  const int wg = blockIdx.y * gx + blockIdx.x;
  const int swz = (wg & 7) * (nwg >> 3) + (wg >> 3);
  const int bcol = swz % gx, brow = swz / gx;

  const unsigned short* Ag = A + (size_t)brow * 256 * K;
  const unsigned short* Bg = B + (size_t)bcol * 256 * K;

  f32x4 acc[8][4] = {};
  const int NT = K >> 6;
  const int NI = NT >> 1;

  // stage one 128x64 half-tile: linear LDS dest (lane*16B), inverse-swizzled global src
  auto stageH = [&](const unsigned short* gbase, unsigned short* ldsh) {
#pragma unroll
    for (int i = 0; i < 2; ++i) {
      int p = i * 4096 + tid * 8;               // physical element offset in half
      int row = p >> 6;                          // 0..127
      int lslot = ((p >> 3) & 7) ^ (row & 7);    // logical 8-elem slot
      gld_lds16(gbase + (size_t)row * K + lslot * 8, ldsh + p);
    }
  };

  const int xsw = (lr & 7) << 3;  // read-side swizzle XOR (element units)
  bf16x8 af[8][2], bf[4][2];

#define RD_A(MLO, SRC) \
  _Pragma("unroll") for (int m = MLO; m < MLO + 4; ++m) { \
    int r = wr * 128 + m * 16 + lr; \
    af[m][0] = *(const bf16x8*)&SRC[(r * 64 + lk * 8) ^ xsw]; \
    af[m][1] = *(const bf16x8*)&SRC[(r * 64 + 32 + lk * 8) ^ xsw]; }
#define RD_B(NLO, SRC) \
  _Pragma("unroll") for (int n = NLO; n < NLO + 2; ++n) { \
    int r = wc * 64 + n * 16 + lr; \
    bf[n][0] = *(const bf16x8*)&SRC[(r * 64 + lk * 8) ^ xsw]; \
    bf[n][1] = *(const bf16x8*)&SRC[(r * 64 + 32 + lk * 8) ^ xsw]; }
#define PH_MFMA(MLO, NLO) \
  __builtin_amdgcn_s_barrier(); \
  asm volatile("s_waitcnt lgkmcnt(0)" ::: "memory"); \
  __builtin_amdgcn_sched_barrier(0); \
  __builtin_amdgcn_s_setprio(1); \
  _Pragma("unroll") for (int m = MLO; m < MLO + 4; ++m) \
  _Pragma("unroll") for (int n = NLO; n < NLO + 2; ++n) \
  _Pragma("unroll") for (int ks = 0; ks < 2; ++ks) \
    acc[m][n] = __builtin_amdgcn_mfma_f32_16x16x32_bf16(af[m][ks], bf[n][ks], acc[m][n], 0, 0, 0); \
  __builtin_amdgcn_s_setprio(0);

  // ---------------- prologue: stage tiles 0 and 1 fully; drain; barrier ----------------
  stageH(Ag, &lA[0][0]);
  stageH(Ag + (size_t)128 * K, &lA[0][8192]);
  stageH(Bg, &lB[0][0]);
  stageH(Bg + (size_t)128 * K, &lB[0][8192]);
  stageH(Ag + 64, &lA[1][0]);
  stageH(Ag + (size_t)128 * K + 64, &lA[1][8192]);
  stageH(Bg + 64, &lB[1][0]);
  stageH(Bg + (size_t)128 * K + 64, &lB[1][8192]);
  VMCNT(0);
  __builtin_amdgcn_s_barrier();

  const unsigned short* lA0 = &lA[0][0];
  const unsigned short* lB0 = &lB[0][0];
  const unsigned short* lA1 = &lA[1][0];
  const unsigned short* lB1 = &lB[1][0];

  for (int it = 0; it < NI; ++it) {
    const int t = it << 1;
    const size_t kT1 = (size_t)(t + 1) * 64;
    const size_t kS2 = (size_t)((t + 2 < NT) ? t + 2 : NT - 1) * 64;
    const size_t kS3 = (size_t)((t + 3 < NT) ? t + 3 : NT - 1) * 64;

    // ---- ph1: rd af[0-3]+bf[0-1] (12) | stage A.H1(t+1) | lgkm(8) | Q(0,0)
    RD_A(0, lA0); RD_B(0, lB0);
    if (it > 0) stageH(Ag + (size_t)128 * K + kT1, &lA[1][8192]);
    asm volatile("s_waitcnt lgkmcnt(8)" ::: "memory");
    PH_MFMA(0, 0);
    __builtin_amdgcn_s_barrier();

    // ---- ph2: rd bf[2-3] (4) | Q(0,2)
    RD_B(2, lB0);
    PH_MFMA(0, 2);
    __builtin_amdgcn_s_barrier();

    // ---- ph3: rd af[4-7] (8) | stage B.H0(t+2) | Q(4,0)
    RD_A(4, lA0);
    stageH(Bg + kS2, &lB[0][0]);
    PH_MFMA(4, 0);
    __builtin_amdgcn_s_barrier();

    // ---- ph4: stage B.H1(t+2), A.H0(t+2) | Q(4,2) | vmcnt(6)
    stageH(Bg + (size_t)128 * K + kS2, &lB[0][8192]);
    stageH(Ag + kS2, &lA[0][0]);
    PH_MFMA(4, 2);
    VMCNT(6);
    __builtin_amdgcn_s_barrier();

    // ---- ph5: rd af[0-3]+bf[0-1] of t+1 | stage A.H1(t+2) | lgkm(8) | Q(0,0)
    RD_A(0, lA1); RD_B(0, lB1);
    stageH(Ag + (size_t)128 * K + kS2, &lA[0][8192]);
    asm volatile("s_waitcnt lgkmcnt(8)" ::: "memory");
    PH_MFMA(0, 0);
    __builtin_amdgcn_s_barrier();

    // ---- ph6: rd bf[2-3] of t+1 | Q(0,2)
    RD_B(2, lB1);
    PH_MFMA(0, 2);
    __builtin_amdgcn_s_barrier();

    // ---- ph7: rd af[4-7] of t+1 | stage B.H0(t+3) | Q(4,0)
    RD_A(4, lA1);
    stageH(Bg + kS3, &lB[1][0]);
    PH_MFMA(4, 0);
    __builtin_amdgcn_s_barrier();

    // ---- ph8: stage B.H1(t+3), A.H0(t+3) | Q(4,2) | vmcnt(6)
    stageH(Bg + (size_t)128 * K + kS3, &lB[1][8192]);
    stageH(Ag + kS3, &lA[1][0]);
    PH_MFMA(4, 2);
    VMCNT(6);
    __builtin_amdgcn_s_barrier();
  }
  VMCNT(0);  // drain tail stages before any wave exits (LDS dealloc safety)

#undef RD_A
#undef RD_B
#undef PH_MFMA

  // Epilogue. C/D frag layout (measured, m89/m91): col = lane&15, row = (lane>>4)*4 + j
  const int row0 = brow * 256 + wr * 128 + lk * 4;
  const int col0 = bcol * 256 + wc * 64 + lr;
#pragma unroll
  for (int m = 0; m < 8; ++m) {
#pragma unroll
    for (int n = 0; n < 4; ++n) {
#pragma unroll
      for (int j = 0; j < 4; ++j) {
        size_t idx = (size_t)(row0 + m * 16 + j) * N + (col0 + n * 16);
        float v = acc[m][n][j];
        if constexpr (EPI == 0) {
          ((float*)Cout)[idx] = v;
        } else if constexpr (EPI == 1) {
          ((unsigned short*)Cout)[idx] = f2bf_rne(v);
        } else {
          float g = bf2f(Gate[idx]);
          float s = g / (1.0f + __expf(-g));  // silu
          ((unsigned short*)Cout)[idx] = f2bf_rne(s * v);
        }
      }
    }
  }
}

extern "C" void kernel_launch(void* const* d_in, const int* in_sizes, int n_in,
                              void* d_out, int out_size, void* d_ws, size_t ws_size,
                              hipStream_t stream) {
  const float* x  = (const float*)d_in[0];
  const float* w1 = (const float*)d_in[1];
  const float* w2 = (const float*)d_in[2];
  const float* w3 = (const float*)d_in[3];
  float* out = (float*)d_out;

  const int M = M_ROWS, E = E_DIM, H = H_DIM;

  // ws layout (bf16 elements):
  //   [0, 32MB)   xb   (reused for w3b after up-GEMM)
  //   [32, 64MB)  w1b  (reused for w2b after gate-GEMM)
  //   [64, 192MB) gate -> h (silu-mul written in-place)
  unsigned short* xb  = (unsigned short*)d_ws;
  unsigned short* w1b = xb + (size_t)M * E;
  unsigned short* gb  = w1b + (size_t)H * E;
  unsigned short* w2b = w1b;  // safe: cvt(w2) is stream-ordered after gate-GEMM reads w1b
  unsigned short* w3b = xb;   // safe: cvt(w3) is stream-ordered after up-GEMM reads xb

  const int n8 = (M * E) / 8;  // == (H*E)/8 == (E*H)/8 == 2097152
  cvt_f32_bf16<<<dim3(n8 / 256), 256, 0, stream>>>(x, xb, n8);
  cvt_f32_bf16<<<dim3(n8 / 256), 256, 0, stream>>>(w1, w1b, n8);

  // gate = x w1^T  -> bf16 [M, H]
  gemm256<1><<<dim3(H / 256, M / 256), 512, 0, stream>>>(xb, w1b, nullptr, gb, M, H, E);

  cvt_f32_bf16<<<dim3(n8 / 256), 256, 0, stream>>>(w2, w2b, n8);

  // h = silu(gate) * (x w2^T) -> bf16 [M, H], in-place over gate
  gemm256<2><<<dim3(H / 256, M / 256), 512, 0, stream>>>(xb, w2b, gb, gb, M, H, E);

  cvt_f32_bf16<<<dim3(n8 / 256), 256, 0, stream>>>(w3, w3b, n8);

  // out = h w3^T -> fp32 [M, E]
  gemm256<0><<<dim3(E / 256, M / 256), 512, 0, stream>>>(gb, w3b, nullptr, out, M, E, H);
}